// Round 5
// baseline (369.572 us; speedup 1.0000x reference)
//
#include <hip/hip_runtime.h>
#include <stdint.h>

typedef unsigned short u16;
typedef __attribute__((ext_vector_type(8))) short bf16x8;
typedef __attribute__((ext_vector_type(4))) float f32x4;

__device__ __forceinline__ u16 f2bf(float f) {
  union { float f; uint32_t u; } v; v.f = f;
  uint32_t u = v.u;
  return (u16)((u + 0x7fffu + ((u >> 16) & 1u)) >> 16);
}

__device__ __forceinline__ void gl_lds16(const void* g, void* l) {
  __builtin_amdgcn_global_load_lds(
      (const __attribute__((address_space(1))) uint32_t*)g,
      (__attribute__((address_space(3))) uint32_t*)l, 16, 0, 0);
}

__constant__ int c_off[9] = {0, 1024, 1808, 2384, 2784, 3040, 3184, 3248, 3264};

// ---------------------------------------------------------------------------
// Fused prep kernel (R11 + R15 vectorized transpose stores).
// ---------------------------------------------------------------------------
__global__ __launch_bounds__(256)
void prep_all(const float* __restrict__ x, u16* __restrict__ Xb,
              const float* __restrict__ lA, u16* __restrict__ lAb,
              const float* __restrict__ ip_w, u16* __restrict__ ip_wt,
              const float* __restrict__ out_w, u16* __restrict__ out_wt,
              const float* __restrict__ lB, u16* __restrict__ lBt,
              const float* w1, const float* w2, const float* w3, const float* w4,
              const float* w5, const float* w6, const float* w7, const float* w8,
              const float* __restrict__ cb,
              u16* __restrict__ Wct, float* __restrict__ bias_c) {
  __shared__ float tile[64][65];
  int b = blockIdx.x;
  const int t = threadIdx.x;
  if (b < 512) {
    const int i = b * 256 + t;
    const float4 v = ((const float4*)x)[i];
    ((ushort4*)Xb)[i] = make_ushort4(f2bf(v.x), f2bf(v.y), f2bf(v.z), f2bf(v.w));
    return;
  }
  b -= 512;
  if (b < 256) {
    const int i = b * 256 + t;
    const float4 v = ((const float4*)lA)[i];
    ((ushort4*)lAb)[i] = make_ushort4(f2bf(v.x), f2bf(v.y), f2bf(v.z), f2bf(v.w));
    return;
  }
  b -= 256;
  if (b < 1392) {
    const float* src; u16* dst; int R, C, bx, by;
    if (b < 816)        { src = ip_w;  dst = ip_wt;  R = 3264; C = 1024; bx = b % 16; by = b / 16; }
    else if (b < 1328)  { b -= 816;  src = out_w; dst = out_wt; R = 1024; C = 1968; bx = b % 32; by = b / 32; }
    else                { b -= 1328; src = lB;    dst = lBt;    R = 64;   C = 4096; bx = b;      by = 0; }
    const int rb = by << 6, cbs = bx << 6;
    for (int i = 0; i < 16; ++i) {
      const int idx = t + (i << 8);
      const int r = idx >> 6, c = idx & 63;
      float v = 0.f;
      if (cbs + c < C) v = src[(size_t)(rb + r) * C + cbs + c];
      tile[r][c] = v;
    }
    __syncthreads();
    const int c = t & 63, q = t >> 6;
    u16* dcol = dst + (size_t)(cbs + c) * R + rb;
    for (int v4 = 0; v4 < 4; ++v4) {
      const int r0 = (q << 4) + (v4 << 2);
      *(ushort4*)(dcol + r0) = make_ushort4(
          f2bf(tile[r0][c]), f2bf(tile[r0 + 1][c]),
          f2bf(tile[r0 + 2][c]), f2bf(tile[r0 + 3][c]));
    }
    return;
  }
  const int o = b - 1392;
  u16* row = Wct + (size_t)o * 512;
  if (t < 128) *(ushort4*)(row + (t << 2)) = make_ushort4(0, 0, 0, 0);
  if (o >= 3264) {
    if (t == 0) bias_c[o] = 0.f;
    return;
  }
  __syncthreads();
  const float* ws[8] = {w1, w2, w3, w4, w5, w6, w7, w8};
  int kidx = 0;
  while (o >= c_off[kidx + 1]) ++kidx;
  const int ks = kidx + 1;
  const int s  = 8 - kidx;
  const int r  = o - c_off[kidx];
  const int f   = r / (s * s);
  const int rem = r - f * s * s;
  const int oi  = rem / s;
  const int oj  = rem - oi * s;
  const float* w = ws[kidx] + (size_t)f * 8 * ks * ks;
  const int ne = 8 * ks * ks;
  for (int e = t; e < ne; e += 256) {
    const int c  = e / (ks * ks);
    const int er = e - c * ks * ks;
    const int di = er / ks;
    const int dj = er - di * ks;
    row[((oi + di) * 8 + (oj + dj)) * 8 + c] = f2bf(w[(c * ks + di) * ks + dj]);
  }
  if (t == 0) bias_c[o] = cb[kidx * 16 + f];
}

// ---------------------------------------------------------------------------
// R16 GEMM body: kk-split wave specialization. t2/t3 were measured LDS-port
// bound (144 KB per CU-K-step = 72 B/cy = 85% of the 85 B/cy ds_read_b128
// ceiling; MFMA 31%, HBM 22%). LDS reads scale with wave-tile perimeter x K:
// the old 32x64 wave-tile read its A-half + B-quarter TWICE (once per kk).
// New: 4 waves = 2 K-halves (p) x 2 N-halves (q); each wave computes the
// full-M 64x(BN/2) tile for ONE kk, accumulating its half-K partial across
// the whole loop; one 2-barrier LDS reduction merges p=0/p=1 at the end.
// Reads/wave/K-step: 12 KB -> 8 KB (block 72 -> 56 KB, -22%) at identical
// occupancy (8 waves/CU), staging, and grid.
// EPI 0: outf = acc (f32 partial)   EPI 1: relu(acc+st_in) -> outf?,outb
// EPI 2: acc+bias -> outf, cg<nvalid  EPI 3: relu(acc+bias) -> outb
// ---------------------------------------------------------------------------
template<int EPI, int NR>
__device__ __forceinline__
void gemm_body(char* lds,
               const u16* __restrict__ A, int lda,
               const u16* __restrict__ Bt, int ldb, int K,
               const float* __restrict__ bias,
               const float* __restrict__ st_in, int st_ld,
               float* __restrict__ outf, int outf_ld,
               u16* __restrict__ outb, int outb_ld, int nvalid,
               int mb, int nb, int stf_c0) {
  constexpr int BN = NR * 32;
  u16 (*As)[64 * 64] = reinterpret_cast<u16 (*)[64 * 64]>(lds);
  u16 (*Bs)[BN * 64] = reinterpret_cast<u16 (*)[BN * 64]>(lds + 2 * 64 * 64 * 2);
  const int t = threadIdx.x;
  const int w = t >> 6, lane = t & 63;
  const int p = w & 1, q = w >> 1;          // p: K-half, q: N-half
  const int n0 = q * (NR << 4);
  const int lr = lane & 15, lq = lane >> 4;

  f32x4 acc[4][NR] = {};
  const int nk = K >> 6;

  auto stage = [&](int kt, int buf) {
    const int kb = kt << 6;
#pragma unroll
    for (int i = 0; i < 2; ++i) {
      const int c   = (w << 7) + (i << 6) + lane;
      const int row = c >> 3;
      const int kg  = (c & 7) ^ (row & 7);
      gl_lds16(A + (size_t)(mb + row) * lda + kb + (kg << 3),
               (char*)As[buf] + c * 16);
    }
#pragma unroll
    for (int i = 0; i < NR; ++i) {
      const int c   = w * (NR * 64) + (i << 6) + lane;
      const int row = c >> 3;
      const int kg  = (c & 7) ^ (row & 7);
      gl_lds16(Bt + (size_t)(nb + row) * ldb + kb + (kg << 3),
               (char*)Bs[buf] + c * 16);
    }
  };

  const int kg = (p << 2) + lq;             // this wave's fixed K-slot
  const int sw = (kg ^ (lr & 7)) << 3;

  stage(0, 0);
  for (int kt = 0; kt < nk; ++kt) {
    const int buf = kt & 1;
    __syncthreads();
    if (kt + 1 < nk) stage(kt + 1, buf ^ 1);
    bf16x8 af[4], bf[NR];
#pragma unroll
    for (int i = 0; i < 4; ++i)
      af[i] = *(const bf16x8*)&As[buf][((i << 4) + lr) * 64 + sw];
#pragma unroll
    for (int j = 0; j < NR; ++j)
      bf[j] = *(const bf16x8*)&Bs[buf][(n0 + (j << 4) + lr) * 64 + sw];
#pragma unroll
    for (int i = 0; i < 4; ++i)
#pragma unroll
      for (int j = 0; j < NR; ++j)
        acc[i][j] = __builtin_amdgcn_mfma_f32_16x16x32_bf16(af[i], bf[j], acc[i][j], 0, 0, 0);
  }

  // Cross-p reduction: p=1 parks its half-K partials in LDS (lane-stride 4B
  // = 2-way bank alias, free); p=0 merges and runs the epilogue.
  __syncthreads();
  float* red = (float*)lds;
  const int rbase = q * (4 * NR * 4 * 64);
  if (p == 1) {
#pragma unroll
    for (int i = 0; i < 4; ++i)
#pragma unroll
      for (int j = 0; j < NR; ++j)
#pragma unroll
        for (int r = 0; r < 4; ++r)
          red[rbase + (((i * NR + j) << 2) + r) * 64 + lane] = acc[i][j][r];
  }
  __syncthreads();
  if (p == 1) return;
#pragma unroll
  for (int i = 0; i < 4; ++i)
#pragma unroll
    for (int j = 0; j < NR; ++j)
#pragma unroll
      for (int r = 0; r < 4; ++r)
        acc[i][j][r] += red[rbase + (((i * NR + j) << 2) + r) * 64 + lane];

#pragma unroll
  for (int i = 0; i < 4; ++i) {
#pragma unroll
    for (int j = 0; j < NR; ++j) {
      const int cg = nb + n0 + (j << 4) + lr;
#pragma unroll
      for (int r = 0; r < 4; ++r) {
        const int rg = mb + (i << 4) + (lq << 2) + r;
        float v = acc[i][j][r];
        if (EPI == 0) {
          outf[(size_t)rg * outf_ld + cg] = v;
        } else if (EPI == 1) {
          v += st_in[(size_t)rg * st_ld + cg];
          v = v > 0.f ? v : 0.f;
          if (cg >= stf_c0) outf[(size_t)rg * outf_ld + cg] = v;
          outb[(size_t)rg * outb_ld + cg] = f2bf(v);
        } else if (EPI == 2) {
          if (cg < nvalid)
            outf[(size_t)rg * outf_ld + cg] = v + bias[cg];
        } else {
          v += bias[cg];
          v = v > 0.f ? v : 0.f;
          outb[(size_t)rg * outb_ld + cg] = f2bf(v);
        }
      }
    }
  }
}

template<int EPI, int NR>
__global__ __launch_bounds__(256)
void gemm128(const u16* __restrict__ A, int lda,
             const u16* __restrict__ Bt, int ldb, int K,
             const float* __restrict__ bias,
             const float* __restrict__ st_in, int st_ld,
             float* __restrict__ outf, int outf_ld,
             u16* __restrict__ outb, int outb_ld, int nvalid, int stf_c0) {
  __shared__ __align__(16) char lds[2 * 64 * 64 * 2 + 2 * NR * 32 * 64 * 2];
  gemm_body<EPI, NR>(lds, A, lda, Bt, ldb, K, bias, st_in, st_ld,
                     outf, outf_ld, outb, outb_ld, nvalid,
                     blockIdx.y << 6, blockIdx.x * (NR * 32), stf_c0);
}

// ---------------------------------------------------------------------------
// R15 fused weff2 + conv-GEMM (conv blocks first; weff HBM wave overlaps).
// ---------------------------------------------------------------------------
__global__ __launch_bounds__(256)
void weff_conv(const float* __restrict__ W, const u16* __restrict__ lBt,
               const u16* __restrict__ lAb, u16* __restrict__ Wt,
               const u16* __restrict__ Xb, const u16* __restrict__ Wct,
               const float* __restrict__ bias_c, u16* __restrict__ feat) {
  __shared__ __align__(16) char lds[49152];
  const int b = blockIdx.x;
  const int t = threadIdx.x;
  if (b < 416) {
    const int bx = b % 26, by = b / 26;
    gemm_body<3, 4>(lds, Xb, 512, Wct, 512, 512, bias_c, nullptr, 0,
                    nullptr, 0, feat, 3328, 3328, by << 6, bx << 7, 0);
    return;
  }
  u16*   As_ = (u16*)lds;
  u16*   Bs_ = (u16*)(lds + 8192);
  float* Wl  = (float*)(lds + 16384);
  u16*   Ct  = (u16*)(lds + 32768);
  const int b2 = b - 416;
  const int w = t >> 6, lane = t & 63;
  const int nb = (b2 & 63) << 6, kb = (b2 >> 6) << 6;
  const int m0 = (w & 1) << 5, n0 = (w >> 1) << 5;
  const int lr = lane & 15, lq = lane >> 4;

  for (int i = 0; i < 2; ++i) {
    const int c   = (w << 7) + (i << 6) + lane;
    const int row = c >> 3;
    const int kg  = (c & 7) ^ (row & 7);
    gl_lds16(lBt + (size_t)(nb + row) * 64 + (kg << 3), (char*)As_ + c * 16);
    gl_lds16(lAb + (size_t)(kb + row) * 64 + (kg << 3), (char*)Bs_ + c * 16);
  }
  for (int i = 0; i < 4; ++i) {
    const int c   = (w << 8) + (i << 6) + lane;
    const int row = c >> 4;
    const int cc  = (c & 15) ^ (row & 15);
    gl_lds16(W + (size_t)(kb + row) * 4096 + nb + (cc << 2), (char*)Wl + c * 16);
  }
  __syncthreads();

  f32x4 acc[2][2] = {};
  for (int kk = 0; kk < 2; ++kk) {
    const int kg = (kk << 2) + lq;
    const int sw = (kg ^ (lr & 7)) << 3;
    bf16x8 af[2], bf[2];
    for (int i = 0; i < 2; ++i)
      af[i] = *(const bf16x8*)&As_[(m0 + (i << 4) + lr) * 64 + sw];
    for (int j = 0; j < 2; ++j)
      bf[j] = *(const bf16x8*)&Bs_[(n0 + (j << 4) + lr) * 64 + sw];
    for (int i = 0; i < 2; ++i)
      for (int j = 0; j < 2; ++j)
        acc[i][j] = __builtin_amdgcn_mfma_f32_16x16x32_bf16(af[i], bf[j], acc[i][j], 0, 0, 0);
  }

  for (int i = 0; i < 2; ++i) {
    for (int j = 0; j < 2; ++j) {
      const int cg  = n0 + (j << 4) + lr;
      const int rg0 = m0 + (i << 4) + (lq << 2);
      const int ch  = (rg0 >> 2) ^ (cg & 15);
      const float4 wv4 = *(const float4*)&Wl[cg * 64 + (ch << 2)];
      const float wv[4] = {wv4.x, wv4.y, wv4.z, wv4.w};
      for (int r = 0; r < 4; ++r)
        Ct[(rg0 + r) * 68 + cg] =
            (wv[r] != 0.f) ? f2bf(wv[r] + 2.0f * acc[i][j][r]) : (u16)0;
    }
  }
  __syncthreads();

  const int row = t >> 2, kp = (t & 3) << 4;
  u16* dst = Wt + (size_t)(nb + row) * 4096 + kb + kp;
  const u16* src = &Ct[row * 68 + kp];
  for (int i = 0; i < 4; ++i)
    *(ushort4*)(dst + (i << 2)) = *(const ushort4*)(src + (i << 2));
}

// ---------------------------------------------------------------------------
// E-stage GEMM, split-K=4 (z: 13,13,13,12 K-iters from k0 = z*832).
// ---------------------------------------------------------------------------
__global__ __launch_bounds__(256)
void gemm_e(const u16* __restrict__ A, const u16* __restrict__ Bt,
            float* __restrict__ part) {
  __shared__ __align__(16) char lds[49152];
  const int z = blockIdx.z;
  const int k0 = z * 832;
  const int nk = (z == 3) ? 12 : 13;
  gemm_body<0, 4>(lds, A + k0, 3328, Bt + k0, 3264, nk << 6,
                  nullptr, nullptr, 0, part + ((size_t)z << 20), 1024,
                  nullptr, 0, 0, blockIdx.y << 6, blockIdx.x << 7, 0);
}

// ---------------------------------------------------------------------------
// t=4 partial GEMM, split-K=4 (grid 1024 = 4 blocks/CU regime).
// ---------------------------------------------------------------------------
__global__ __launch_bounds__(256)
void gemm_p4(const u16* __restrict__ A, const u16* __restrict__ Bt,
             float* __restrict__ part) {
  __shared__ __align__(16) char lds[32768];
  const int z = blockIdx.z;
  gemm_body<0, 2>(lds, A + (z << 10), 4096, Bt + (z << 10), 4096, 1024,
                  nullptr, nullptr, 0, part + ((size_t)z << 20), 1024,
                  nullptr, 0, 0, blockIdx.y << 6, blockIdx.x << 6, 0);
}

// ---------------------------------------------------------------------------
// E combine.
// ---------------------------------------------------------------------------
__global__ __launch_bounds__(256)
void e_combine(const float* __restrict__ part, const float* __restrict__ bias,
               float* __restrict__ st_f, u16* __restrict__ st_b) {
  const int i = (blockIdx.x * 256 + threadIdx.x) << 2;
  const int row = i >> 12, col = i & 4095;
  if (col < 1024) {
    const int pi = (row << 10) + col;
    const float4 a = *(const float4*)&part[pi];
    const float4 b = *(const float4*)&part[1024 * 1024 + pi];
    const float4 c = *(const float4*)&part[2 * 1024 * 1024 + pi];
    const float4 d = *(const float4*)&part[3 * 1024 * 1024 + pi];
    const float4 bs = *(const float4*)&bias[col];
    float v[4] = {a.x + b.x + c.x + d.x + bs.x, a.y + b.y + c.y + d.y + bs.y,
                  a.z + b.z + c.z + d.z + bs.z, a.w + b.w + c.w + d.w + bs.w};
    u16 o[4];
    for (int r = 0; r < 4; ++r) {
      v[r] = v[r] > 0.f ? v[r] : 0.f;
      o[r] = f2bf(v[r]);
    }
    *(float4*)&st_f[i] = make_float4(v[0], v[1], v[2], v[3]);
    *(ushort4*)&st_b[i] = make_ushort4(o[0], o[1], o[2], o[3]);
  } else {
    *(float4*)&st_f[i] = make_float4(0.f, 0.f, 0.f, 0.f);
    *(ushort4*)&st_b[i] = make_ushort4(0, 0, 0, 0);
  }
}

// ---------------------------------------------------------------------------
// t=4 combine (no f32 state store; t4's st_f output is dead).
// ---------------------------------------------------------------------------
__global__ __launch_bounds__(256)
void t4_combine(const float* __restrict__ part, const float* __restrict__ st_in,
                u16* __restrict__ st_b) {
  const int i = (blockIdx.x * 256 + threadIdx.x) << 2;
  const int r = i >> 10, c = i & 1023;
  const float4 a  = *(const float4*)&part[i];
  const float4 b  = *(const float4*)&part[(1 << 20) + i];
  const float4 cc = *(const float4*)&part[(2 << 20) + i];
  const float4 d  = *(const float4*)&part[(3 << 20) + i];
  const float4 s  = *(const float4*)&st_in[(size_t)r * 4096 + 3072 + c];
  float v[4] = {a.x + b.x + cc.x + d.x + s.x, a.y + b.y + cc.y + d.y + s.y,
                a.z + b.z + cc.z + d.z + s.z, a.w + b.w + cc.w + d.w + s.w};
  u16 o[4];
  for (int k = 0; k < 4; ++k) {
    v[k] = v[k] > 0.f ? v[k] : 0.f;
    o[k] = f2bf(v[k]);
  }
  *(ushort4*)&st_b[(size_t)r * 4096 + 3072 + c] = make_ushort4(o[0], o[1], o[2], o[3]);
}

// ---------------------------------------------------------------------------
extern "C" void kernel_launch(void* const* d_in, const int* in_sizes, int n_in,
                              void* d_out, int out_size, void* d_ws, size_t ws_size,
                              hipStream_t stream) {
  const float* x     = (const float*)d_in[0];
  const float* cw[8];
  for (int i = 0; i < 8; ++i) cw[i] = (const float*)d_in[1 + i];
  const float* convb = (const float*)d_in[9];
  const float* W     = (const float*)d_in[10];
  const float* lA    = (const float*)d_in[11];
  const float* lB    = (const float*)d_in[12];
  const float* ip_w  = (const float*)d_in[13];
  const float* ip_b  = (const float*)d_in[14];
  const float* out_w = (const float*)d_in[15];
  const float* out_b = (const float*)d_in[16];
  float* out = (float*)d_out;

  char* p = (char*)d_ws;
  u16* feat   = (u16*)p;  p += (size_t)1024 * 3328 * 2;
  u16* ip_wt  = (u16*)p;  p += (size_t)1024 * 3264 * 2;
  u16* out_wt = (u16*)p;  p += (size_t)2048 * 1024 * 2;
  u16* Wt     = (u16*)p;  p += (size_t)4096 * 4096 * 2;
  float* st_f[2];
  st_f[0] = (float*)p;    p += (size_t)1024 * 4096 * 4;
  st_f[1] = (float*)p;    p += (size_t)1024 * 4096 * 4;
  u16* st_b[2];
  st_b[0] = (u16*)p;      p += (size_t)1024 * 4096 * 2;
  st_b[1] = (u16*)p;      p += (size_t)1024 * 4096 * 2;

  // Prep buffers alias the front of st_f[1]; Epart reuses all of st_f[1];
  // t=4 partials reuse st_f[0] (dead after t3 reads it).
  char* q = (char*)st_f[1];
  u16* Xb       = (u16*)q;  q += (size_t)1024 * 512 * 2;
  u16* Wct      = (u16*)q;  q += (size_t)3328 * 512 * 2;
  float* bias_c = (float*)q; q += (size_t)3328 * 4;
  u16* lBt      = (u16*)q;  q += (size_t)4096 * 64 * 2;
  u16* lAb      = (u16*)q;  q += (size_t)4096 * 64 * 2;
  float* Epart  = (float*)st_f[1];
  float* Tpart  = (float*)st_f[0];

  // 1. fused prep
  prep_all<<<5488, 256, 0, stream>>>(x, Xb, lA, lAb, ip_w, ip_wt,
                                     out_w, out_wt, lB, lBt,
                                     cw[0], cw[1], cw[2], cw[3],
                                     cw[4], cw[5], cw[6], cw[7], convb,
                                     Wct, bias_c);

  // 2. fused W_eff + conv GEMM
  weff_conv<<<4512, 256, 0, stream>>>(W, lBt, lAb, Wt, Xb, Wct, bias_c, feat);

  // 3-4. t=0: split-K=4 E + combine (zeros cols >= 1024)
  gemm_e<<<dim3(8, 16, 4), 256, 0, stream>>>(feat, ip_wt, Epart);
  e_combine<<<4096, 256, 0, stream>>>(Epart, ip_b, st_f[0], st_b[0]);

  // 5. t=1: state cols >= 1024 are EXACTLY zero -> K=1024 (bit-identical)
  gemm128<1, 4><<<dim3(32, 16), 256, 0, stream>>>(st_b[0], 4096, Wt, 4096, 1024,
      nullptr, st_f[0], 4096, st_f[1], 4096, st_b[1], 4096, 4096, 0);

  // 6-7. t=2,3: full K=4096, N=4096; t3's f32 store predicated to cols>=3072
  gemm128<1, 4><<<dim3(32, 16), 256, 0, stream>>>(st_b[1], 4096, Wt, 4096, 4096,
      nullptr, st_f[1], 4096, st_f[0], 4096, st_b[0], 4096, 4096, 0);
  gemm128<1, 4><<<dim3(32, 16), 256, 0, stream>>>(st_b[0], 4096, Wt, 4096, 4096,
      nullptr, st_f[0], 4096, st_f[1], 4096, st_b[1], 4096, 4096, 3072);

  // 8-9. t=4: N=1024 (Wt rows 3072+), split-K=4
  gemm_p4<<<dim3(16, 16, 4), 256, 0, stream>>>(st_b[1],
      Wt + (size_t)3072 * 4096, Tpart);
  t4_combine<<<1024, 256, 0, stream>>>(Tpart, st_f[1], st_b[0]);

  // 10. output: state[:, 3072:] @ out_w + out_b
  gemm128<2, 2><<<dim3(32, 16), 256, 0, stream>>>(st_b[0] + 3072, 4096, out_wt, 1024, 1024,
      out_b, nullptr, 0, out, 1968, nullptr, 0, 1968, 0);
}

// Round 6
// 350.017 us; speedup vs baseline: 1.0559x; 1.0559x over previous
//
#include <hip/hip_runtime.h>
#include <stdint.h>

typedef unsigned short u16;
typedef __attribute__((ext_vector_type(8))) short bf16x8;
typedef __attribute__((ext_vector_type(4))) float f32x4;

__device__ __forceinline__ u16 f2bf(float f) {
  union { float f; uint32_t u; } v; v.f = f;
  uint32_t u = v.u;
  return (u16)((u + 0x7fffu + ((u >> 16) & 1u)) >> 16);
}

__device__ __forceinline__ void gl_lds16(const void* g, void* l) {
  __builtin_amdgcn_global_load_lds(
      (const __attribute__((address_space(1))) uint32_t*)g,
      (__attribute__((address_space(3))) uint32_t*)l, 16, 0, 0);
}

__constant__ int c_off[9] = {0, 1024, 1808, 2384, 2784, 3040, 3184, 3248, 3264};

// ---------------------------------------------------------------------------
// Fused prep kernel (R11 + R15 vectorized transpose stores).
// ---------------------------------------------------------------------------
__global__ __launch_bounds__(256)
void prep_all(const float* __restrict__ x, u16* __restrict__ Xb,
              const float* __restrict__ lA, u16* __restrict__ lAb,
              const float* __restrict__ ip_w, u16* __restrict__ ip_wt,
              const float* __restrict__ out_w, u16* __restrict__ out_wt,
              const float* __restrict__ lB, u16* __restrict__ lBt,
              const float* w1, const float* w2, const float* w3, const float* w4,
              const float* w5, const float* w6, const float* w7, const float* w8,
              const float* __restrict__ cb,
              u16* __restrict__ Wct, float* __restrict__ bias_c) {
  __shared__ float tile[64][65];
  int b = blockIdx.x;
  const int t = threadIdx.x;
  if (b < 512) {
    const int i = b * 256 + t;
    const float4 v = ((const float4*)x)[i];
    ((ushort4*)Xb)[i] = make_ushort4(f2bf(v.x), f2bf(v.y), f2bf(v.z), f2bf(v.w));
    return;
  }
  b -= 512;
  if (b < 256) {
    const int i = b * 256 + t;
    const float4 v = ((const float4*)lA)[i];
    ((ushort4*)lAb)[i] = make_ushort4(f2bf(v.x), f2bf(v.y), f2bf(v.z), f2bf(v.w));
    return;
  }
  b -= 256;
  if (b < 1392) {
    const float* src; u16* dst; int R, C, bx, by;
    if (b < 816)        { src = ip_w;  dst = ip_wt;  R = 3264; C = 1024; bx = b % 16; by = b / 16; }
    else if (b < 1328)  { b -= 816;  src = out_w; dst = out_wt; R = 1024; C = 1968; bx = b % 32; by = b / 32; }
    else                { b -= 1328; src = lB;    dst = lBt;    R = 64;   C = 4096; bx = b;      by = 0; }
    const int rb = by << 6, cbs = bx << 6;
    for (int i = 0; i < 16; ++i) {
      const int idx = t + (i << 8);
      const int r = idx >> 6, c = idx & 63;
      float v = 0.f;
      if (cbs + c < C) v = src[(size_t)(rb + r) * C + cbs + c];
      tile[r][c] = v;
    }
    __syncthreads();
    const int c = t & 63, q = t >> 6;
    u16* dcol = dst + (size_t)(cbs + c) * R + rb;
    for (int v4 = 0; v4 < 4; ++v4) {
      const int r0 = (q << 4) + (v4 << 2);
      *(ushort4*)(dcol + r0) = make_ushort4(
          f2bf(tile[r0][c]), f2bf(tile[r0 + 1][c]),
          f2bf(tile[r0 + 2][c]), f2bf(tile[r0 + 3][c]));
    }
    return;
  }
  const int o = b - 1392;
  u16* row = Wct + (size_t)o * 512;
  if (t < 128) *(ushort4*)(row + (t << 2)) = make_ushort4(0, 0, 0, 0);
  if (o >= 3264) {
    if (t == 0) bias_c[o] = 0.f;
    return;
  }
  __syncthreads();
  const float* ws[8] = {w1, w2, w3, w4, w5, w6, w7, w8};
  int kidx = 0;
  while (o >= c_off[kidx + 1]) ++kidx;
  const int ks = kidx + 1;
  const int s  = 8 - kidx;
  const int r  = o - c_off[kidx];
  const int f   = r / (s * s);
  const int rem = r - f * s * s;
  const int oi  = rem / s;
  const int oj  = rem - oi * s;
  const float* w = ws[kidx] + (size_t)f * 8 * ks * ks;
  const int ne = 8 * ks * ks;
  for (int e = t; e < ne; e += 256) {
    const int c  = e / (ks * ks);
    const int er = e - c * ks * ks;
    const int di = er / ks;
    const int dj = er - di * ks;
    row[((oi + di) * 8 + (oj + dj)) * 8 + c] = f2bf(w[(c * ks + di) * ks + dj]);
  }
  if (t == 0) bias_c[o] = cb[kidx * 16 + f];
}

// ---------------------------------------------------------------------------
// R15 GEMM body (reverted from R16's kk-split, which regressed): 64x(NR*32)
// tile, 4 waves, wave-tile 32x(NR*16), BK=64, dbuf LDS via __syncthreads,
// XOR-swizzled, gl_lds staging.
// EPI 0: outf = acc (f32 partial)   EPI 1: relu(acc+st_in) -> outf?,outb
// EPI 2: acc+bias -> outf, cg<nvalid  EPI 3: relu(acc+bias) -> outb
// ---------------------------------------------------------------------------
template<int EPI, int NR>
__device__ __forceinline__
void gemm_body(char* lds,
               const u16* __restrict__ A, int lda,
               const u16* __restrict__ Bt, int ldb, int K,
               const float* __restrict__ bias,
               const float* __restrict__ st_in, int st_ld,
               float* __restrict__ outf, int outf_ld,
               u16* __restrict__ outb, int outb_ld, int nvalid,
               int mb, int nb, int stf_c0) {
  constexpr int BN = NR * 32;
  u16 (*As)[64 * 64] = reinterpret_cast<u16 (*)[64 * 64]>(lds);
  u16 (*Bs)[BN * 64] = reinterpret_cast<u16 (*)[BN * 64]>(lds + 2 * 64 * 64 * 2);
  const int t = threadIdx.x;
  const int w = t >> 6, lane = t & 63;
  const int m0 = (w & 1) << 5, n0 = (w >> 1) * (NR << 4);
  const int lr = lane & 15, lq = lane >> 4;

  f32x4 acc[2][NR] = {};
  const int nk = K >> 6;

  auto stage = [&](int kt, int buf) {
    const int kb = kt << 6;
#pragma unroll
    for (int i = 0; i < 2; ++i) {
      const int c   = (w << 7) + (i << 6) + lane;
      const int row = c >> 3;
      const int kg  = (c & 7) ^ (row & 7);
      gl_lds16(A + (size_t)(mb + row) * lda + kb + (kg << 3),
               (char*)As[buf] + c * 16);
    }
#pragma unroll
    for (int i = 0; i < NR; ++i) {
      const int c   = w * (NR * 64) + (i << 6) + lane;
      const int row = c >> 3;
      const int kg  = (c & 7) ^ (row & 7);
      gl_lds16(Bt + (size_t)(nb + row) * ldb + kb + (kg << 3),
               (char*)Bs[buf] + c * 16);
    }
  };

  stage(0, 0);
  for (int kt = 0; kt < nk; ++kt) {
    const int buf = kt & 1;
    __syncthreads();
    if (kt + 1 < nk) stage(kt + 1, buf ^ 1);
#pragma unroll
    for (int kk = 0; kk < 2; ++kk) {
      const int kg = (kk << 2) + lq;
      const int sw = (kg ^ (lr & 7)) << 3;
      bf16x8 af[2], bf[NR];
#pragma unroll
      for (int i = 0; i < 2; ++i)
        af[i] = *(const bf16x8*)&As[buf][(m0 + (i << 4) + lr) * 64 + sw];
#pragma unroll
      for (int j = 0; j < NR; ++j)
        bf[j] = *(const bf16x8*)&Bs[buf][(n0 + (j << 4) + lr) * 64 + sw];
#pragma unroll
      for (int i = 0; i < 2; ++i)
#pragma unroll
        for (int j = 0; j < NR; ++j)
          acc[i][j] = __builtin_amdgcn_mfma_f32_16x16x32_bf16(af[i], bf[j], acc[i][j], 0, 0, 0);
    }
  }

#pragma unroll
  for (int i = 0; i < 2; ++i) {
#pragma unroll
    for (int j = 0; j < NR; ++j) {
      const int cg = nb + n0 + (j << 4) + lr;
#pragma unroll
      for (int r = 0; r < 4; ++r) {
        const int rg = mb + m0 + (i << 4) + (lq << 2) + r;
        float v = acc[i][j][r];
        if (EPI == 0) {
          outf[(size_t)rg * outf_ld + cg] = v;
        } else if (EPI == 1) {
          v += st_in[(size_t)rg * st_ld + cg];
          v = v > 0.f ? v : 0.f;
          if (cg >= stf_c0) outf[(size_t)rg * outf_ld + cg] = v;
          outb[(size_t)rg * outb_ld + cg] = f2bf(v);
        } else if (EPI == 2) {
          if (cg < nvalid)
            outf[(size_t)rg * outf_ld + cg] = v + bias[cg];
        } else {
          v += bias[cg];
          v = v > 0.f ? v : 0.f;
          outb[(size_t)rg * outb_ld + cg] = f2bf(v);
        }
      }
    }
  }
}

template<int EPI, int NR>
__global__ __launch_bounds__(256)
void gemm128(const u16* __restrict__ A, int lda,
             const u16* __restrict__ Bt, int ldb, int K,
             const float* __restrict__ bias,
             const float* __restrict__ st_in, int st_ld,
             float* __restrict__ outf, int outf_ld,
             u16* __restrict__ outb, int outb_ld, int nvalid, int stf_c0) {
  __shared__ __align__(16) char lds[2 * 64 * 64 * 2 + 2 * NR * 32 * 64 * 2];
  gemm_body<EPI, NR>(lds, A, lda, Bt, ldb, K, bias, st_in, st_ld,
                     outf, outf_ld, outb, outb_ld, nvalid,
                     blockIdx.y << 6, blockIdx.x * (NR * 32), stf_c0);
}

// ---------------------------------------------------------------------------
// R17: 512-thread 8-wave recurrent GEMM (t1/t2/t3). Latency-bound diagnosis:
// all counters low simultaneously (MfmaUtil 25, VALU 20, HBM 22%, conflicts
// 0, occ 19%) and both traffic-reduction probes (R14/R16) regressed while
// waves/CU probes tracked the m102 curve. Same 64x128 tile, same grid
// (512 = 2 blocks/CU), same swizzle and staging bytes -- but 8 waves/block
// (wave-tile 32x32, acc[2][2]) = 16 waves/CU, doubling the latency-hiding
// pool. LDS 48KB/block (96KB/CU).
// ---------------------------------------------------------------------------
__global__ __launch_bounds__(512)
void gemm512e1(const u16* __restrict__ A, int lda,
               const u16* __restrict__ Bt, int ldb, int K,
               const float* __restrict__ st_in, int st_ld,
               float* __restrict__ outf, int outf_ld,
               u16* __restrict__ outb, int outb_ld, int stf_c0) {
  __shared__ __align__(16) u16 As[2][64 * 64];
  __shared__ __align__(16) u16 Bs[2][128 * 64];
  const int t = threadIdx.x;
  const int w = t >> 6, lane = t & 63;
  const int mb = blockIdx.y << 6, nb = blockIdx.x << 7;
  const int m0 = (w & 1) << 5, n0 = (w >> 1) << 5;
  const int lr = lane & 15, lq = lane >> 4;

  f32x4 acc[2][2] = {};
  const int nk = K >> 6;

  auto stage = [&](int kt, int buf) {
    const int kb = kt << 6;
    {
      const int c   = t;                       // A: 512 lanes cover 64x64
      const int row = c >> 3;
      const int kg  = (c & 7) ^ (row & 7);
      gl_lds16(A + (size_t)(mb + row) * lda + kb + (kg << 3),
               (char*)As[buf] + c * 16);
    }
#pragma unroll
    for (int i = 0; i < 2; ++i) {              // B: 2 per lane cover 128x64
      const int c   = (i << 9) + t;
      const int row = c >> 3;
      const int kg  = (c & 7) ^ (row & 7);
      gl_lds16(Bt + (size_t)(nb + row) * ldb + kb + (kg << 3),
               (char*)Bs[buf] + c * 16);
    }
  };

  stage(0, 0);
  for (int kt = 0; kt < nk; ++kt) {
    const int buf = kt & 1;
    __syncthreads();
    if (kt + 1 < nk) stage(kt + 1, buf ^ 1);
#pragma unroll
    for (int kk = 0; kk < 2; ++kk) {
      const int kg = (kk << 2) + lq;
      const int sw = (kg ^ (lr & 7)) << 3;
      bf16x8 af[2], bf[2];
#pragma unroll
      for (int i = 0; i < 2; ++i)
        af[i] = *(const bf16x8*)&As[buf][(m0 + (i << 4) + lr) * 64 + sw];
#pragma unroll
      for (int j = 0; j < 2; ++j)
        bf[j] = *(const bf16x8*)&Bs[buf][(n0 + (j << 4) + lr) * 64 + sw];
#pragma unroll
      for (int i = 0; i < 2; ++i)
#pragma unroll
        for (int j = 0; j < 2; ++j)
          acc[i][j] = __builtin_amdgcn_mfma_f32_16x16x32_bf16(af[i], bf[j], acc[i][j], 0, 0, 0);
    }
  }

#pragma unroll
  for (int i = 0; i < 2; ++i)
#pragma unroll
    for (int j = 0; j < 2; ++j) {
      const int cg = nb + n0 + (j << 4) + lr;
#pragma unroll
      for (int r = 0; r < 4; ++r) {
        const int rg = mb + m0 + (i << 4) + (lq << 2) + r;
        float v = acc[i][j][r] + st_in[(size_t)rg * st_ld + cg];
        v = v > 0.f ? v : 0.f;
        if (cg >= stf_c0) outf[(size_t)rg * outf_ld + cg] = v;
        outb[(size_t)rg * outb_ld + cg] = f2bf(v);
      }
    }
}

// ---------------------------------------------------------------------------
// R15 fused weff2 + conv-GEMM (conv blocks first; weff HBM wave overlaps).
// ---------------------------------------------------------------------------
__global__ __launch_bounds__(256)
void weff_conv(const float* __restrict__ W, const u16* __restrict__ lBt,
               const u16* __restrict__ lAb, u16* __restrict__ Wt,
               const u16* __restrict__ Xb, const u16* __restrict__ Wct,
               const float* __restrict__ bias_c, u16* __restrict__ feat) {
  __shared__ __align__(16) char lds[49152];
  const int b = blockIdx.x;
  const int t = threadIdx.x;
  if (b < 416) {
    const int bx = b % 26, by = b / 26;
    gemm_body<3, 4>(lds, Xb, 512, Wct, 512, 512, bias_c, nullptr, 0,
                    nullptr, 0, feat, 3328, 3328, by << 6, bx << 7, 0);
    return;
  }
  u16*   As_ = (u16*)lds;
  u16*   Bs_ = (u16*)(lds + 8192);
  float* Wl  = (float*)(lds + 16384);
  u16*   Ct  = (u16*)(lds + 32768);
  const int b2 = b - 416;
  const int w = t >> 6, lane = t & 63;
  const int nb = (b2 & 63) << 6, kb = (b2 >> 6) << 6;
  const int m0 = (w & 1) << 5, n0 = (w >> 1) << 5;
  const int lr = lane & 15, lq = lane >> 4;

  for (int i = 0; i < 2; ++i) {
    const int c   = (w << 7) + (i << 6) + lane;
    const int row = c >> 3;
    const int kg  = (c & 7) ^ (row & 7);
    gl_lds16(lBt + (size_t)(nb + row) * 64 + (kg << 3), (char*)As_ + c * 16);
    gl_lds16(lAb + (size_t)(kb + row) * 64 + (kg << 3), (char*)Bs_ + c * 16);
  }
  for (int i = 0; i < 4; ++i) {
    const int c   = (w << 8) + (i << 6) + lane;
    const int row = c >> 4;
    const int cc  = (c & 15) ^ (row & 15);
    gl_lds16(W + (size_t)(kb + row) * 4096 + nb + (cc << 2), (char*)Wl + c * 16);
  }
  __syncthreads();

  f32x4 acc[2][2] = {};
  for (int kk = 0; kk < 2; ++kk) {
    const int kg = (kk << 2) + lq;
    const int sw = (kg ^ (lr & 7)) << 3;
    bf16x8 af[2], bf[2];
    for (int i = 0; i < 2; ++i)
      af[i] = *(const bf16x8*)&As_[(m0 + (i << 4) + lr) * 64 + sw];
    for (int j = 0; j < 2; ++j)
      bf[j] = *(const bf16x8*)&Bs_[(n0 + (j << 4) + lr) * 64 + sw];
    for (int i = 0; i < 2; ++i)
      for (int j = 0; j < 2; ++j)
        acc[i][j] = __builtin_amdgcn_mfma_f32_16x16x32_bf16(af[i], bf[j], acc[i][j], 0, 0, 0);
  }

  for (int i = 0; i < 2; ++i) {
    for (int j = 0; j < 2; ++j) {
      const int cg  = n0 + (j << 4) + lr;
      const int rg0 = m0 + (i << 4) + (lq << 2);
      const int ch  = (rg0 >> 2) ^ (cg & 15);
      const float4 wv4 = *(const float4*)&Wl[cg * 64 + (ch << 2)];
      const float wv[4] = {wv4.x, wv4.y, wv4.z, wv4.w};
      for (int r = 0; r < 4; ++r)
        Ct[(rg0 + r) * 68 + cg] =
            (wv[r] != 0.f) ? f2bf(wv[r] + 2.0f * acc[i][j][r]) : (u16)0;
    }
  }
  __syncthreads();

  const int row = t >> 2, kp = (t & 3) << 4;
  u16* dst = Wt + (size_t)(nb + row) * 4096 + kb + kp;
  const u16* src = &Ct[row * 68 + kp];
  for (int i = 0; i < 4; ++i)
    *(ushort4*)(dst + (i << 2)) = *(const ushort4*)(src + (i << 2));
}

// ---------------------------------------------------------------------------
// E-stage GEMM, split-K=4 (z: 13,13,13,12 K-iters from k0 = z*832).
// ---------------------------------------------------------------------------
__global__ __launch_bounds__(256)
void gemm_e(const u16* __restrict__ A, const u16* __restrict__ Bt,
            float* __restrict__ part) {
  __shared__ __align__(16) char lds[49152];
  const int z = blockIdx.z;
  const int k0 = z * 832;
  const int nk = (z == 3) ? 12 : 13;
  gemm_body<0, 4>(lds, A + k0, 3328, Bt + k0, 3264, nk << 6,
                  nullptr, nullptr, 0, part + ((size_t)z << 20), 1024,
                  nullptr, 0, 0, blockIdx.y << 6, blockIdx.x << 7, 0);
}

// ---------------------------------------------------------------------------
// t=4 partial GEMM, split-K=4 (grid 1024 = 4 blocks/CU regime).
// ---------------------------------------------------------------------------
__global__ __launch_bounds__(256)
void gemm_p4(const u16* __restrict__ A, const u16* __restrict__ Bt,
             float* __restrict__ part) {
  __shared__ __align__(16) char lds[32768];
  const int z = blockIdx.z;
  gemm_body<0, 2>(lds, A + (z << 10), 4096, Bt + (z << 10), 4096, 1024,
                  nullptr, nullptr, 0, part + ((size_t)z << 20), 1024,
                  nullptr, 0, 0, blockIdx.y << 6, blockIdx.x << 6, 0);
}

// ---------------------------------------------------------------------------
// E combine.
// ---------------------------------------------------------------------------
__global__ __launch_bounds__(256)
void e_combine(const float* __restrict__ part, const float* __restrict__ bias,
               float* __restrict__ st_f, u16* __restrict__ st_b) {
  const int i = (blockIdx.x * 256 + threadIdx.x) << 2;
  const int row = i >> 12, col = i & 4095;
  if (col < 1024) {
    const int pi = (row << 10) + col;
    const float4 a = *(const float4*)&part[pi];
    const float4 b = *(const float4*)&part[1024 * 1024 + pi];
    const float4 c = *(const float4*)&part[2 * 1024 * 1024 + pi];
    const float4 d = *(const float4*)&part[3 * 1024 * 1024 + pi];
    const float4 bs = *(const float4*)&bias[col];
    float v[4] = {a.x + b.x + c.x + d.x + bs.x, a.y + b.y + c.y + d.y + bs.y,
                  a.z + b.z + c.z + d.z + bs.z, a.w + b.w + c.w + d.w + bs.w};
    u16 o[4];
    for (int r = 0; r < 4; ++r) {
      v[r] = v[r] > 0.f ? v[r] : 0.f;
      o[r] = f2bf(v[r]);
    }
    *(float4*)&st_f[i] = make_float4(v[0], v[1], v[2], v[3]);
    *(ushort4*)&st_b[i] = make_ushort4(o[0], o[1], o[2], o[3]);
  } else {
    *(float4*)&st_f[i] = make_float4(0.f, 0.f, 0.f, 0.f);
    *(ushort4*)&st_b[i] = make_ushort4(0, 0, 0, 0);
  }
}

// ---------------------------------------------------------------------------
// t=4 combine (no f32 state store; t4's st_f output is dead).
// ---------------------------------------------------------------------------
__global__ __launch_bounds__(256)
void t4_combine(const float* __restrict__ part, const float* __restrict__ st_in,
                u16* __restrict__ st_b) {
  const int i = (blockIdx.x * 256 + threadIdx.x) << 2;
  const int r = i >> 10, c = i & 1023;
  const float4 a  = *(const float4*)&part[i];
  const float4 b  = *(const float4*)&part[(1 << 20) + i];
  const float4 cc = *(const float4*)&part[(2 << 20) + i];
  const float4 d  = *(const float4*)&part[(3 << 20) + i];
  const float4 s  = *(const float4*)&st_in[(size_t)r * 4096 + 3072 + c];
  float v[4] = {a.x + b.x + cc.x + d.x + s.x, a.y + b.y + cc.y + d.y + s.y,
                a.z + b.z + cc.z + d.z + s.z, a.w + b.w + cc.w + d.w + s.w};
  u16 o[4];
  for (int k = 0; k < 4; ++k) {
    v[k] = v[k] > 0.f ? v[k] : 0.f;
    o[k] = f2bf(v[k]);
  }
  *(ushort4*)&st_b[(size_t)r * 4096 + 3072 + c] = make_ushort4(o[0], o[1], o[2], o[3]);
}

// ---------------------------------------------------------------------------
extern "C" void kernel_launch(void* const* d_in, const int* in_sizes, int n_in,
                              void* d_out, int out_size, void* d_ws, size_t ws_size,
                              hipStream_t stream) {
  const float* x     = (const float*)d_in[0];
  const float* cw[8];
  for (int i = 0; i < 8; ++i) cw[i] = (const float*)d_in[1 + i];
  const float* convb = (const float*)d_in[9];
  const float* W     = (const float*)d_in[10];
  const float* lA    = (const float*)d_in[11];
  const float* lB    = (const float*)d_in[12];
  const float* ip_w  = (const float*)d_in[13];
  const float* ip_b  = (const float*)d_in[14];
  const float* out_w = (const float*)d_in[15];
  const float* out_b = (const float*)d_in[16];
  float* out = (float*)d_out;

  char* p = (char*)d_ws;
  u16* feat   = (u16*)p;  p += (size_t)1024 * 3328 * 2;
  u16* ip_wt  = (u16*)p;  p += (size_t)1024 * 3264 * 2;
  u16* out_wt = (u16*)p;  p += (size_t)2048 * 1024 * 2;
  u16* Wt     = (u16*)p;  p += (size_t)4096 * 4096 * 2;
  float* st_f[2];
  st_f[0] = (float*)p;    p += (size_t)1024 * 4096 * 4;
  st_f[1] = (float*)p;    p += (size_t)1024 * 4096 * 4;
  u16* st_b[2];
  st_b[0] = (u16*)p;      p += (size_t)1024 * 4096 * 2;
  st_b[1] = (u16*)p;      p += (size_t)1024 * 4096 * 2;

  // Prep buffers alias the front of st_f[1]; Epart reuses all of st_f[1];
  // t=4 partials reuse st_f[0] (dead after t3 reads it).
  char* q = (char*)st_f[1];
  u16* Xb       = (u16*)q;  q += (size_t)1024 * 512 * 2;
  u16* Wct      = (u16*)q;  q += (size_t)3328 * 512 * 2;
  float* bias_c = (float*)q; q += (size_t)3328 * 4;
  u16* lBt      = (u16*)q;  q += (size_t)4096 * 64 * 2;
  u16* lAb      = (u16*)q;  q += (size_t)4096 * 64 * 2;
  float* Epart  = (float*)st_f[1];
  float* Tpart  = (float*)st_f[0];

  // 1. fused prep
  prep_all<<<5488, 256, 0, stream>>>(x, Xb, lA, lAb, ip_w, ip_wt,
                                     out_w, out_wt, lB, lBt,
                                     cw[0], cw[1], cw[2], cw[3],
                                     cw[4], cw[5], cw[6], cw[7], convb,
                                     Wct, bias_c);

  // 2. fused W_eff + conv GEMM
  weff_conv<<<4512, 256, 0, stream>>>(W, lBt, lAb, Wt, Xb, Wct, bias_c, feat);

  // 3-4. t=0: split-K=4 E + combine (zeros cols >= 1024)
  gemm_e<<<dim3(8, 16, 4), 256, 0, stream>>>(feat, ip_wt, Epart);
  e_combine<<<4096, 256, 0, stream>>>(Epart, ip_b, st_f[0], st_b[0]);

  // 5. t=1: state cols >= 1024 are EXACTLY zero -> K=1024 (bit-identical)
  gemm512e1<<<dim3(32, 16), 512, 0, stream>>>(st_b[0], 4096, Wt, 4096, 1024,
      st_f[0], 4096, st_f[1], 4096, st_b[1], 4096, 0);

  // 6-7. t=2,3: full K=4096, N=4096; t3's f32 store predicated to cols>=3072
  gemm512e1<<<dim3(32, 16), 512, 0, stream>>>(st_b[1], 4096, Wt, 4096, 4096,
      st_f[1], 4096, st_f[0], 4096, st_b[0], 4096, 0);
  gemm512e1<<<dim3(32, 16), 512, 0, stream>>>(st_b[0], 4096, Wt, 4096, 4096,
      st_f[0], 4096, st_f[1], 4096, st_b[1], 4096, 3072);

  // 8-9. t=4: N=1024 (Wt rows 3072+), split-K=4
  gemm_p4<<<dim3(16, 16, 4), 256, 0, stream>>>(st_b[1],
      Wt + (size_t)3072 * 4096, Tpart);
  t4_combine<<<1024, 256, 0, stream>>>(Tpart, st_f[1], st_b[0]);

  // 10. output: state[:, 3072:] @ out_w + out_b
  gemm128<2, 2><<<dim3(32, 16), 256, 0, stream>>>(st_b[0] + 3072, 4096, out_wt, 1024, 1024,
      out_b, nullptr, 0, out, 1968, nullptr, 0, 1968, 0);
}

// Round 7
// 346.149 us; speedup vs baseline: 1.0677x; 1.0112x over previous
//
#include <hip/hip_runtime.h>
#include <stdint.h>

typedef unsigned short u16;
typedef __attribute__((ext_vector_type(8))) short bf16x8;
typedef __attribute__((ext_vector_type(4))) float f32x4;

__device__ __forceinline__ u16 f2bf(float f) {
  union { float f; uint32_t u; } v; v.f = f;
  uint32_t u = v.u;
  return (u16)((u + 0x7fffu + ((u >> 16) & 1u)) >> 16);
}

__device__ __forceinline__ void gl_lds16(const void* g, void* l) {
  __builtin_amdgcn_global_load_lds(
      (const __attribute__((address_space(1))) uint32_t*)g,
      (__attribute__((address_space(3))) uint32_t*)l, 16, 0, 0);
}

__constant__ int c_off[9] = {0, 1024, 1808, 2384, 2784, 3040, 3184, 3248, 3264};

// ---------------------------------------------------------------------------
// Fused prep kernel (R11 + R15 vectorized transpose stores).
// ---------------------------------------------------------------------------
__global__ __launch_bounds__(256)
void prep_all(const float* __restrict__ x, u16* __restrict__ Xb,
              const float* __restrict__ lA, u16* __restrict__ lAb,
              const float* __restrict__ ip_w, u16* __restrict__ ip_wt,
              const float* __restrict__ out_w, u16* __restrict__ out_wt,
              const float* __restrict__ lB, u16* __restrict__ lBt,
              const float* w1, const float* w2, const float* w3, const float* w4,
              const float* w5, const float* w6, const float* w7, const float* w8,
              const float* __restrict__ cb,
              u16* __restrict__ Wct, float* __restrict__ bias_c) {
  __shared__ float tile[64][65];
  int b = blockIdx.x;
  const int t = threadIdx.x;
  if (b < 512) {
    const int i = b * 256 + t;
    const float4 v = ((const float4*)x)[i];
    ((ushort4*)Xb)[i] = make_ushort4(f2bf(v.x), f2bf(v.y), f2bf(v.z), f2bf(v.w));
    return;
  }
  b -= 512;
  if (b < 256) {
    const int i = b * 256 + t;
    const float4 v = ((const float4*)lA)[i];
    ((ushort4*)lAb)[i] = make_ushort4(f2bf(v.x), f2bf(v.y), f2bf(v.z), f2bf(v.w));
    return;
  }
  b -= 256;
  if (b < 1392) {
    const float* src; u16* dst; int R, C, bx, by;
    if (b < 816)        { src = ip_w;  dst = ip_wt;  R = 3264; C = 1024; bx = b % 16; by = b / 16; }
    else if (b < 1328)  { b -= 816;  src = out_w; dst = out_wt; R = 1024; C = 1968; bx = b % 32; by = b / 32; }
    else                { b -= 1328; src = lB;    dst = lBt;    R = 64;   C = 4096; bx = b;      by = 0; }
    const int rb = by << 6, cbs = bx << 6;
    for (int i = 0; i < 16; ++i) {
      const int idx = t + (i << 8);
      const int r = idx >> 6, c = idx & 63;
      float v = 0.f;
      if (cbs + c < C) v = src[(size_t)(rb + r) * C + cbs + c];
      tile[r][c] = v;
    }
    __syncthreads();
    const int c = t & 63, q = t >> 6;
    u16* dcol = dst + (size_t)(cbs + c) * R + rb;
    for (int v4 = 0; v4 < 4; ++v4) {
      const int r0 = (q << 4) + (v4 << 2);
      *(ushort4*)(dcol + r0) = make_ushort4(
          f2bf(tile[r0][c]), f2bf(tile[r0 + 1][c]),
          f2bf(tile[r0 + 2][c]), f2bf(tile[r0 + 3][c]));
    }
    return;
  }
  const int o = b - 1392;
  u16* row = Wct + (size_t)o * 512;
  if (t < 128) *(ushort4*)(row + (t << 2)) = make_ushort4(0, 0, 0, 0);
  if (o >= 3264) {
    if (t == 0) bias_c[o] = 0.f;
    return;
  }
  __syncthreads();
  const float* ws[8] = {w1, w2, w3, w4, w5, w6, w7, w8};
  int kidx = 0;
  while (o >= c_off[kidx + 1]) ++kidx;
  const int ks = kidx + 1;
  const int s  = 8 - kidx;
  const int r  = o - c_off[kidx];
  const int f   = r / (s * s);
  const int rem = r - f * s * s;
  const int oi  = rem / s;
  const int oj  = rem - oi * s;
  const float* w = ws[kidx] + (size_t)f * 8 * ks * ks;
  const int ne = 8 * ks * ks;
  for (int e = t; e < ne; e += 256) {
    const int c  = e / (ks * ks);
    const int er = e - c * ks * ks;
    const int di = er / ks;
    const int dj = er - di * ks;
    row[((oi + di) * 8 + (oj + dj)) * 8 + c] = f2bf(w[(c * ks + di) * ks + dj]);
  }
  if (t == 0) bias_c[o] = cb[kidx * 16 + f];
}

// ---------------------------------------------------------------------------
// R15 GEMM body: 64x(NR*32) tile, 4 waves, wave-tile 32x(NR*16), BK=64,
// dbuf LDS via __syncthreads, XOR-swizzled, gl_lds staging.
// EPI 0: outf = acc (f32 partial)   EPI 1: relu(acc+st_in) -> outf?,outb
// EPI 2: acc+bias -> outf, cg<nvalid  EPI 3: relu(acc+bias) -> outb
// R18: t2/t3 use NR=2 at grid (64,16) = 1024 blocks = 4 blocks/CU (the
// 833-TF point on the m102 blocks/CU curve; 64x128 was stuck at 2/CU).
// ---------------------------------------------------------------------------
template<int EPI, int NR>
__device__ __forceinline__
void gemm_body(char* lds,
               const u16* __restrict__ A, int lda,
               const u16* __restrict__ Bt, int ldb, int K,
               const float* __restrict__ bias,
               const float* __restrict__ st_in, int st_ld,
               float* __restrict__ outf, int outf_ld,
               u16* __restrict__ outb, int outb_ld, int nvalid,
               int mb, int nb, int stf_c0) {
  constexpr int BN = NR * 32;
  u16 (*As)[64 * 64] = reinterpret_cast<u16 (*)[64 * 64]>(lds);
  u16 (*Bs)[BN * 64] = reinterpret_cast<u16 (*)[BN * 64]>(lds + 2 * 64 * 64 * 2);
  const int t = threadIdx.x;
  const int w = t >> 6, lane = t & 63;
  const int m0 = (w & 1) << 5, n0 = (w >> 1) * (NR << 4);
  const int lr = lane & 15, lq = lane >> 4;

  f32x4 acc[2][NR] = {};
  const int nk = K >> 6;

  auto stage = [&](int kt, int buf) {
    const int kb = kt << 6;
#pragma unroll
    for (int i = 0; i < 2; ++i) {
      const int c   = (w << 7) + (i << 6) + lane;
      const int row = c >> 3;
      const int kg  = (c & 7) ^ (row & 7);
      gl_lds16(A + (size_t)(mb + row) * lda + kb + (kg << 3),
               (char*)As[buf] + c * 16);
    }
#pragma unroll
    for (int i = 0; i < NR; ++i) {
      const int c   = w * (NR * 64) + (i << 6) + lane;
      const int row = c >> 3;
      const int kg  = (c & 7) ^ (row & 7);
      gl_lds16(Bt + (size_t)(nb + row) * ldb + kb + (kg << 3),
               (char*)Bs[buf] + c * 16);
    }
  };

  stage(0, 0);
  for (int kt = 0; kt < nk; ++kt) {
    const int buf = kt & 1;
    __syncthreads();
    if (kt + 1 < nk) stage(kt + 1, buf ^ 1);
#pragma unroll
    for (int kk = 0; kk < 2; ++kk) {
      const int kg = (kk << 2) + lq;
      const int sw = (kg ^ (lr & 7)) << 3;
      bf16x8 af[2], bf[NR];
#pragma unroll
      for (int i = 0; i < 2; ++i)
        af[i] = *(const bf16x8*)&As[buf][(m0 + (i << 4) + lr) * 64 + sw];
#pragma unroll
      for (int j = 0; j < NR; ++j)
        bf[j] = *(const bf16x8*)&Bs[buf][(n0 + (j << 4) + lr) * 64 + sw];
#pragma unroll
      for (int i = 0; i < 2; ++i)
#pragma unroll
        for (int j = 0; j < NR; ++j)
          acc[i][j] = __builtin_amdgcn_mfma_f32_16x16x32_bf16(af[i], bf[j], acc[i][j], 0, 0, 0);
    }
  }

#pragma unroll
  for (int i = 0; i < 2; ++i) {
#pragma unroll
    for (int j = 0; j < NR; ++j) {
      const int cg = nb + n0 + (j << 4) + lr;
#pragma unroll
      for (int r = 0; r < 4; ++r) {
        const int rg = mb + m0 + (i << 4) + (lq << 2) + r;
        float v = acc[i][j][r];
        if (EPI == 0) {
          outf[(size_t)rg * outf_ld + cg] = v;
        } else if (EPI == 1) {
          v += st_in[(size_t)rg * st_ld + cg];
          v = v > 0.f ? v : 0.f;
          if (cg >= stf_c0) outf[(size_t)rg * outf_ld + cg] = v;
          outb[(size_t)rg * outb_ld + cg] = f2bf(v);
        } else if (EPI == 2) {
          if (cg < nvalid)
            outf[(size_t)rg * outf_ld + cg] = v + bias[cg];
        } else {
          v += bias[cg];
          v = v > 0.f ? v : 0.f;
          outb[(size_t)rg * outb_ld + cg] = f2bf(v);
        }
      }
    }
  }
}

template<int EPI, int NR>
__global__ __launch_bounds__(256)
void gemm128(const u16* __restrict__ A, int lda,
             const u16* __restrict__ Bt, int ldb, int K,
             const float* __restrict__ bias,
             const float* __restrict__ st_in, int st_ld,
             float* __restrict__ outf, int outf_ld,
             u16* __restrict__ outb, int outb_ld, int nvalid, int stf_c0) {
  __shared__ __align__(16) char lds[2 * 64 * 64 * 2 + 2 * NR * 32 * 64 * 2];
  gemm_body<EPI, NR>(lds, A, lda, Bt, ldb, K, bias, st_in, st_ld,
                     outf, outf_ld, outb, outb_ld, nvalid,
                     blockIdx.y << 6, blockIdx.x * (NR * 32), stf_c0);
}

// ---------------------------------------------------------------------------
// R17 t1 kernel (kept: 8-wave 512-thread, ~10us faster on the
// epilogue-heavy K=1024 step -- 2x waves = 2x memory parallelism).
// ---------------------------------------------------------------------------
__global__ __launch_bounds__(512)
void gemm512e1(const u16* __restrict__ A, int lda,
               const u16* __restrict__ Bt, int ldb, int K,
               const float* __restrict__ st_in, int st_ld,
               float* __restrict__ outf, int outf_ld,
               u16* __restrict__ outb, int outb_ld, int stf_c0) {
  __shared__ __align__(16) u16 As[2][64 * 64];
  __shared__ __align__(16) u16 Bs[2][128 * 64];
  const int t = threadIdx.x;
  const int w = t >> 6, lane = t & 63;
  const int mb = blockIdx.y << 6, nb = blockIdx.x << 7;
  const int m0 = (w & 1) << 5, n0 = (w >> 1) << 5;
  const int lr = lane & 15, lq = lane >> 4;

  f32x4 acc[2][2] = {};
  const int nk = K >> 6;

  auto stage = [&](int kt, int buf) {
    const int kb = kt << 6;
    {
      const int c   = t;
      const int row = c >> 3;
      const int kg  = (c & 7) ^ (row & 7);
      gl_lds16(A + (size_t)(mb + row) * lda + kb + (kg << 3),
               (char*)As[buf] + c * 16);
    }
#pragma unroll
    for (int i = 0; i < 2; ++i) {
      const int c   = (i << 9) + t;
      const int row = c >> 3;
      const int kg  = (c & 7) ^ (row & 7);
      gl_lds16(Bt + (size_t)(nb + row) * ldb + kb + (kg << 3),
               (char*)Bs[buf] + c * 16);
    }
  };

  stage(0, 0);
  for (int kt = 0; kt < nk; ++kt) {
    const int buf = kt & 1;
    __syncthreads();
    if (kt + 1 < nk) stage(kt + 1, buf ^ 1);
#pragma unroll
    for (int kk = 0; kk < 2; ++kk) {
      const int kg = (kk << 2) + lq;
      const int sw = (kg ^ (lr & 7)) << 3;
      bf16x8 af[2], bf[2];
#pragma unroll
      for (int i = 0; i < 2; ++i)
        af[i] = *(const bf16x8*)&As[buf][(m0 + (i << 4) + lr) * 64 + sw];
#pragma unroll
      for (int j = 0; j < 2; ++j)
        bf[j] = *(const bf16x8*)&Bs[buf][(n0 + (j << 4) + lr) * 64 + sw];
#pragma unroll
      for (int i = 0; i < 2; ++i)
#pragma unroll
        for (int j = 0; j < 2; ++j)
          acc[i][j] = __builtin_amdgcn_mfma_f32_16x16x32_bf16(af[i], bf[j], acc[i][j], 0, 0, 0);
    }
  }

#pragma unroll
  for (int i = 0; i < 2; ++i)
#pragma unroll
    for (int j = 0; j < 2; ++j) {
      const int cg = nb + n0 + (j << 4) + lr;
#pragma unroll
      for (int r = 0; r < 4; ++r) {
        const int rg = mb + m0 + (i << 4) + (lq << 2) + r;
        float v = acc[i][j][r] + st_in[(size_t)rg * st_ld + cg];
        v = v > 0.f ? v : 0.f;
        if (cg >= stf_c0) outf[(size_t)rg * outf_ld + cg] = v;
        outb[(size_t)rg * outb_ld + cg] = f2bf(v);
      }
    }
}

// ---------------------------------------------------------------------------
// R15 fused weff2 + conv-GEMM (conv blocks first; weff HBM wave overlaps).
// ---------------------------------------------------------------------------
__global__ __launch_bounds__(256)
void weff_conv(const float* __restrict__ W, const u16* __restrict__ lBt,
               const u16* __restrict__ lAb, u16* __restrict__ Wt,
               const u16* __restrict__ Xb, const u16* __restrict__ Wct,
               const float* __restrict__ bias_c, u16* __restrict__ feat) {
  __shared__ __align__(16) char lds[49152];
  const int b = blockIdx.x;
  const int t = threadIdx.x;
  if (b < 416) {
    const int bx = b % 26, by = b / 26;
    gemm_body<3, 4>(lds, Xb, 512, Wct, 512, 512, bias_c, nullptr, 0,
                    nullptr, 0, feat, 3328, 3328, by << 6, bx << 7, 0);
    return;
  }
  u16*   As_ = (u16*)lds;
  u16*   Bs_ = (u16*)(lds + 8192);
  float* Wl  = (float*)(lds + 16384);
  u16*   Ct  = (u16*)(lds + 32768);
  const int b2 = b - 416;
  const int w = t >> 6, lane = t & 63;
  const int nb = (b2 & 63) << 6, kb = (b2 >> 6) << 6;
  const int m0 = (w & 1) << 5, n0 = (w >> 1) << 5;
  const int lr = lane & 15, lq = lane >> 4;

  for (int i = 0; i < 2; ++i) {
    const int c   = (w << 7) + (i << 6) + lane;
    const int row = c >> 3;
    const int kg  = (c & 7) ^ (row & 7);
    gl_lds16(lBt + (size_t)(nb + row) * 64 + (kg << 3), (char*)As_ + c * 16);
    gl_lds16(lAb + (size_t)(kb + row) * 64 + (kg << 3), (char*)Bs_ + c * 16);
  }
  for (int i = 0; i < 4; ++i) {
    const int c   = (w << 8) + (i << 6) + lane;
    const int row = c >> 4;
    const int cc  = (c & 15) ^ (row & 15);
    gl_lds16(W + (size_t)(kb + row) * 4096 + nb + (cc << 2), (char*)Wl + c * 16);
  }
  __syncthreads();

  f32x4 acc[2][2] = {};
  for (int kk = 0; kk < 2; ++kk) {
    const int kg = (kk << 2) + lq;
    const int sw = (kg ^ (lr & 7)) << 3;
    bf16x8 af[2], bf[2];
    for (int i = 0; i < 2; ++i)
      af[i] = *(const bf16x8*)&As_[(m0 + (i << 4) + lr) * 64 + sw];
    for (int j = 0; j < 2; ++j)
      bf[j] = *(const bf16x8*)&Bs_[(n0 + (j << 4) + lr) * 64 + sw];
    for (int i = 0; i < 2; ++i)
      for (int j = 0; j < 2; ++j)
        acc[i][j] = __builtin_amdgcn_mfma_f32_16x16x32_bf16(af[i], bf[j], acc[i][j], 0, 0, 0);
  }

  for (int i = 0; i < 2; ++i) {
    for (int j = 0; j < 2; ++j) {
      const int cg  = n0 + (j << 4) + lr;
      const int rg0 = m0 + (i << 4) + (lq << 2);
      const int ch  = (rg0 >> 2) ^ (cg & 15);
      const float4 wv4 = *(const float4*)&Wl[cg * 64 + (ch << 2)];
      const float wv[4] = {wv4.x, wv4.y, wv4.z, wv4.w};
      for (int r = 0; r < 4; ++r)
        Ct[(rg0 + r) * 68 + cg] =
            (wv[r] != 0.f) ? f2bf(wv[r] + 2.0f * acc[i][j][r]) : (u16)0;
    }
  }
  __syncthreads();

  const int row = t >> 2, kp = (t & 3) << 4;
  u16* dst = Wt + (size_t)(nb + row) * 4096 + kb + kp;
  const u16* src = &Ct[row * 68 + kp];
  for (int i = 0; i < 4; ++i)
    *(ushort4*)(dst + (i << 2)) = *(const ushort4*)(src + (i << 2));
}

// ---------------------------------------------------------------------------
// E-stage GEMM, split-K=4 (z: 13,13,13,12 K-iters from k0 = z*832).
// ---------------------------------------------------------------------------
__global__ __launch_bounds__(256)
void gemm_e(const u16* __restrict__ A, const u16* __restrict__ Bt,
            float* __restrict__ part) {
  __shared__ __align__(16) char lds[49152];
  const int z = blockIdx.z;
  const int k0 = z * 832;
  const int nk = (z == 3) ? 12 : 13;
  gemm_body<0, 4>(lds, A + k0, 3328, Bt + k0, 3264, nk << 6,
                  nullptr, nullptr, 0, part + ((size_t)z << 20), 1024,
                  nullptr, 0, 0, blockIdx.y << 6, blockIdx.x << 7, 0);
}

// ---------------------------------------------------------------------------
// t=4 partial GEMM, split-K=4 (grid 1024 = 4 blocks/CU regime).
// ---------------------------------------------------------------------------
__global__ __launch_bounds__(256)
void gemm_p4(const u16* __restrict__ A, const u16* __restrict__ Bt,
             float* __restrict__ part) {
  __shared__ __align__(16) char lds[32768];
  const int z = blockIdx.z;
  gemm_body<0, 2>(lds, A + (z << 10), 4096, Bt + (z << 10), 4096, 1024,
                  nullptr, nullptr, 0, part + ((size_t)z << 20), 1024,
                  nullptr, 0, 0, blockIdx.y << 6, blockIdx.x << 6, 0);
}

// ---------------------------------------------------------------------------
// E combine.
// ---------------------------------------------------------------------------
__global__ __launch_bounds__(256)
void e_combine(const float* __restrict__ part, const float* __restrict__ bias,
               float* __restrict__ st_f, u16* __restrict__ st_b) {
  const int i = (blockIdx.x * 256 + threadIdx.x) << 2;
  const int row = i >> 12, col = i & 4095;
  if (col < 1024) {
    const int pi = (row << 10) + col;
    const float4 a = *(const float4*)&part[pi];
    const float4 b = *(const float4*)&part[1024 * 1024 + pi];
    const float4 c = *(const float4*)&part[2 * 1024 * 1024 + pi];
    const float4 d = *(const float4*)&part[3 * 1024 * 1024 + pi];
    const float4 bs = *(const float4*)&bias[col];
    float v[4] = {a.x + b.x + c.x + d.x + bs.x, a.y + b.y + c.y + d.y + bs.y,
                  a.z + b.z + c.z + d.z + bs.z, a.w + b.w + c.w + d.w + bs.w};
    u16 o[4];
    for (int r = 0; r < 4; ++r) {
      v[r] = v[r] > 0.f ? v[r] : 0.f;
      o[r] = f2bf(v[r]);
    }
    *(float4*)&st_f[i] = make_float4(v[0], v[1], v[2], v[3]);
    *(ushort4*)&st_b[i] = make_ushort4(o[0], o[1], o[2], o[3]);
  } else {
    *(float4*)&st_f[i] = make_float4(0.f, 0.f, 0.f, 0.f);
    *(ushort4*)&st_b[i] = make_ushort4(0, 0, 0, 0);
  }
}

// ---------------------------------------------------------------------------
// t=4 combine (no f32 state store; t4's st_f output is dead).
// ---------------------------------------------------------------------------
__global__ __launch_bounds__(256)
void t4_combine(const float* __restrict__ part, const float* __restrict__ st_in,
                u16* __restrict__ st_b) {
  const int i = (blockIdx.x * 256 + threadIdx.x) << 2;
  const int r = i >> 10, c = i & 1023;
  const float4 a  = *(const float4*)&part[i];
  const float4 b  = *(const float4*)&part[(1 << 20) + i];
  const float4 cc = *(const float4*)&part[(2 << 20) + i];
  const float4 d  = *(const float4*)&part[(3 << 20) + i];
  const float4 s  = *(const float4*)&st_in[(size_t)r * 4096 + 3072 + c];
  float v[4] = {a.x + b.x + cc.x + d.x + s.x, a.y + b.y + cc.y + d.y + s.y,
                a.z + b.z + cc.z + d.z + s.z, a.w + b.w + cc.w + d.w + s.w};
  u16 o[4];
  for (int k = 0; k < 4; ++k) {
    v[k] = v[k] > 0.f ? v[k] : 0.f;
    o[k] = f2bf(v[k]);
  }
  *(ushort4*)&st_b[(size_t)r * 4096 + 3072 + c] = make_ushort4(o[0], o[1], o[2], o[3]);
}

// ---------------------------------------------------------------------------
extern "C" void kernel_launch(void* const* d_in, const int* in_sizes, int n_in,
                              void* d_out, int out_size, void* d_ws, size_t ws_size,
                              hipStream_t stream) {
  const float* x     = (const float*)d_in[0];
  const float* cw[8];
  for (int i = 0; i < 8; ++i) cw[i] = (const float*)d_in[1 + i];
  const float* convb = (const float*)d_in[9];
  const float* W     = (const float*)d_in[10];
  const float* lA    = (const float*)d_in[11];
  const float* lB    = (const float*)d_in[12];
  const float* ip_w  = (const float*)d_in[13];
  const float* ip_b  = (const float*)d_in[14];
  const float* out_w = (const float*)d_in[15];
  const float* out_b = (const float*)d_in[16];
  float* out = (float*)d_out;

  char* p = (char*)d_ws;
  u16* feat   = (u16*)p;  p += (size_t)1024 * 3328 * 2;
  u16* ip_wt  = (u16*)p;  p += (size_t)1024 * 3264 * 2;
  u16* out_wt = (u16*)p;  p += (size_t)2048 * 1024 * 2;
  u16* Wt     = (u16*)p;  p += (size_t)4096 * 4096 * 2;
  float* st_f[2];
  st_f[0] = (float*)p;    p += (size_t)1024 * 4096 * 4;
  st_f[1] = (float*)p;    p += (size_t)1024 * 4096 * 4;
  u16* st_b[2];
  st_b[0] = (u16*)p;      p += (size_t)1024 * 4096 * 2;
  st_b[1] = (u16*)p;      p += (size_t)1024 * 4096 * 2;

  // Prep buffers alias the front of st_f[1]; Epart reuses all of st_f[1];
  // t=4 partials reuse st_f[0] (dead after t3 reads it).
  char* q = (char*)st_f[1];
  u16* Xb       = (u16*)q;  q += (size_t)1024 * 512 * 2;
  u16* Wct      = (u16*)q;  q += (size_t)3328 * 512 * 2;
  float* bias_c = (float*)q; q += (size_t)3328 * 4;
  u16* lBt      = (u16*)q;  q += (size_t)4096 * 64 * 2;
  u16* lAb      = (u16*)q;  q += (size_t)4096 * 64 * 2;
  float* Epart  = (float*)st_f[1];
  float* Tpart  = (float*)st_f[0];

  // 1. fused prep
  prep_all<<<5488, 256, 0, stream>>>(x, Xb, lA, lAb, ip_w, ip_wt,
                                     out_w, out_wt, lB, lBt,
                                     cw[0], cw[1], cw[2], cw[3],
                                     cw[4], cw[5], cw[6], cw[7], convb,
                                     Wct, bias_c);

  // 2. fused W_eff + conv GEMM
  weff_conv<<<4512, 256, 0, stream>>>(W, lBt, lAb, Wt, Xb, Wct, bias_c, feat);

  // 3-4. t=0: split-K=4 E + combine (zeros cols >= 1024)
  gemm_e<<<dim3(8, 16, 4), 256, 0, stream>>>(feat, ip_wt, Epart);
  e_combine<<<4096, 256, 0, stream>>>(Epart, ip_b, st_f[0], st_b[0]);

  // 5. t=1: K=1024 (cols >= 1024 exactly zero); 8-wave variant (R17 win).
  gemm512e1<<<dim3(32, 16), 512, 0, stream>>>(st_b[0], 4096, Wt, 4096, 1024,
      st_f[0], 4096, st_f[1], 4096, st_b[1], 4096, 0);

  // 6-7. t=2,3: full K=4096, N=4096 at 64x64 tile, grid (64,16) = 1024
  //      blocks = 4 blocks/CU. t3's f32 store predicated to cols >= 3072.
  gemm128<1, 2><<<dim3(64, 16), 256, 0, stream>>>(st_b[1], 4096, Wt, 4096, 4096,
      nullptr, st_f[1], 4096, st_f[0], 4096, st_b[0], 4096, 4096, 0);
  gemm128<1, 2><<<dim3(64, 16), 256, 0, stream>>>(st_b[0], 4096, Wt, 4096, 4096,
      nullptr, st_f[0], 4096, st_f[1], 4096, st_b[1], 4096, 4096, 3072);

  // 8-9. t=4: N=1024 (Wt rows 3072+), split-K=4
  gemm_p4<<<dim3(16, 16, 4), 256, 0, stream>>>(st_b[1],
      Wt + (size_t)3072 * 4096, Tpart);
  t4_combine<<<1024, 256, 0, stream>>>(Tpart, st_f[1], st_b[0]);

  // 10. output: state[:, 3072:] @ out_w + out_b
  gemm128<2, 2><<<dim3(32, 16), 256, 0, stream>>>(st_b[0] + 3072, 4096, out_wt, 1024, 1024,
      out_b, nullptr, 0, out, 1968, nullptr, 0, 1968, 0);
}